// Round 8
// baseline (221.019 us; speedup 1.0000x reference)
//
#include <hip/hip_runtime.h>
#include <float.h>
#include <math.h>

#define BB 32
#define NN 1024
#define DD 128
#define KK 5

typedef __attribute__((ext_vector_type(8))) short bf16x8;
typedef __attribute__((ext_vector_type(4))) float f32x4;
typedef unsigned long long ull;

// rtne f32->bf16 bit trick (no NaN/inf in this problem)
__device__ __forceinline__ unsigned short f2bf(float f) {
    unsigned int u = __float_as_uint(f);
    return (unsigned short)((u + 0x7FFFu + ((u >> 16) & 1u)) >> 16);
}
__device__ __forceinline__ float bf2f(unsigned short h) {
    return __uint_as_float(((unsigned int)h) << 16);
}

// packed sortable key: (orderable(v) << 32) | (1023 - col)
// u64 max == lexicographic (value desc, col asc) == lax.top_k order.
__device__ __forceinline__ ull mkkey(float v, int col) {
    unsigned int u = __float_as_uint(v);
    unsigned int ou = u ^ (unsigned)((((int)u) >> 31) | 0x80000000);
    return ((ull)ou << 32) | (unsigned)(1023 - col);
}

// ---- 1. fused: row L2-normalize + 3-limb bf16 split (h,m,l planes) ------
__global__ __launch_bounds__(256) void k_norm(const float* __restrict__ x,
                                              unsigned short* __restrict__ ph,
                                              unsigned short* __restrict__ pm,
                                              unsigned short* __restrict__ pl) {
    int row  = blockIdx.x * 4 + (threadIdx.x >> 6);
    int lane = threadIdx.x & 63;
    float2 v = *reinterpret_cast<const float2*>(x + (size_t)row * DD + lane * 2);
    float ss = v.x * v.x + v.y * v.y;
#pragma unroll
    for (int o = 32; o >= 1; o >>= 1) ss += __shfl_xor(ss, o);
    float inv = 1.0f / fmaxf(sqrtf(ss), 1e-12f);
    float y0 = v.x * inv, y1 = v.y * inv;

    unsigned short h0 = f2bf(y0);             float r0 = y0 - bf2f(h0);
    unsigned short m0 = f2bf(r0);             float s0 = r0 - bf2f(m0);
    unsigned short l0 = f2bf(s0);
    unsigned short h1 = f2bf(y1);             float r1 = y1 - bf2f(h1);
    unsigned short m1 = f2bf(r1);             float s1 = r1 - bf2f(m1);
    unsigned short l1 = f2bf(s1);

    size_t o = (size_t)row * DD + lane * 2;
    *reinterpret_cast<unsigned int*>(ph + o) = (unsigned int)h0 | ((unsigned int)h1 << 16);
    *reinterpret_cast<unsigned int*>(pm + o) = (unsigned int)m0 | ((unsigned int)m1 << 16);
    *reinterpret_cast<unsigned int*>(pl + o) = (unsigned int)l0 | ((unsigned int)l1 << 16);
}

__device__ __forceinline__ void stage_plane(const unsigned short* __restrict__ g,
                                            unsigned short (*s)[40], int tid,
                                            size_t rowbase, int c) {
#pragma unroll
    for (int hh = 0; hh < 2; ++hh) {
        int u = tid + (hh << 8);
        int row = u >> 2, qq = u & 3;
        const float4 v = *reinterpret_cast<const float4*>(
            g + (rowbase + row) * DD + (c << 5) + (qq << 3));
        *reinterpret_cast<float4*>(&s[row][qq << 3]) = v;
    }
}

// ---- 2. sim tile (6-limb MFMA) + fused butterfly top-5 per segment ------
// upper-tri tiles; row-side + register mirror-side; no sim materialization.
__global__ __launch_bounds__(256, 2) void k_sim(const unsigned short* __restrict__ ph,
                                                const unsigned short* __restrict__ pm,
                                                const unsigned short* __restrict__ pl,
                                                ull* __restrict__ cand) {
    // XCD-chunked bijective swizzle: 1152 = 8 * 144
    int bid = blockIdx.x;
    int lb  = (bid & 7) * 144 + (bid >> 3);
    int bl  = lb / 36;
    int p   = lb - bl * 36;
    int ti = 0;
    while (p >= 8 - ti) { p -= 8 - ti; ++ti; }
    int tj = ti + p;
    int R  = ti << 7, Cc = tj << 7;

    __shared__ struct {
        unsigned short Ah[128][40], Am[128][40], Al[128][40];
        unsigned short Bh[128][40], Bm[128][40], Bl[128][40];
    } sm;   // 61440 B

    int tid  = threadIdx.x;
    int wv   = tid >> 6;
    int lane = tid & 63;
    int wr = (wv >> 1) << 6;
    int wc = (wv & 1) << 6;
    int lg = lane >> 4, fr = lane & 15;

    size_t base = (size_t)bl * NN;
    size_t rbA = base + R, rbB = base + Cc;

    f32x4 acc[4][4];
#pragma unroll
    for (int i = 0; i < 4; ++i)
#pragma unroll
        for (int j = 0; j < 4; ++j) acc[i][j] = (f32x4){0.f, 0.f, 0.f, 0.f};

    int kk = lg << 3;

    for (int c = 0; c < 4; ++c) {
        if (c) __syncthreads();
        stage_plane(ph, sm.Ah, tid, rbA, c);
        stage_plane(pm, sm.Am, tid, rbA, c);
        stage_plane(pl, sm.Al, tid, rbA, c);
        stage_plane(ph, sm.Bh, tid, rbB, c);
        stage_plane(pm, sm.Bm, tid, rbB, c);
        stage_plane(pl, sm.Bl, tid, rbB, c);
        __syncthreads();

        bf16x8 bh[4], bm[4], blo[4];
#pragma unroll
        for (int cp = 0; cp < 4; ++cp) {
            int rb = wc + cp * 16 + fr;
            bh[cp]  = *reinterpret_cast<const bf16x8*>(&sm.Bh[rb][kk]);
            bm[cp]  = *reinterpret_cast<const bf16x8*>(&sm.Bm[rb][kk]);
            blo[cp] = *reinterpret_cast<const bf16x8*>(&sm.Bl[rb][kk]);
        }
#pragma unroll
        for (int rp = 0; rp < 4; ++rp) {
            int ra = wr + rp * 16 + fr;
            bf16x8 ah = *reinterpret_cast<const bf16x8*>(&sm.Ah[ra][kk]);
            bf16x8 am = *reinterpret_cast<const bf16x8*>(&sm.Am[ra][kk]);
            bf16x8 al = *reinterpret_cast<const bf16x8*>(&sm.Al[ra][kk]);
#pragma unroll
            for (int cp = 0; cp < 4; ++cp) {
                f32x4 cacc = acc[rp][cp];
                cacc = __builtin_amdgcn_mfma_f32_16x16x32_bf16(ah, bh[cp],  cacc, 0, 0, 0);
                cacc = __builtin_amdgcn_mfma_f32_16x16x32_bf16(ah, bm[cp],  cacc, 0, 0, 0);
                cacc = __builtin_amdgcn_mfma_f32_16x16x32_bf16(am, bh[cp],  cacc, 0, 0, 0);
                cacc = __builtin_amdgcn_mfma_f32_16x16x32_bf16(ah, blo[cp], cacc, 0, 0, 0);
                cacc = __builtin_amdgcn_mfma_f32_16x16x32_bf16(al, bh[cp],  cacc, 0, 0, 0);
                cacc = __builtin_amdgcn_mfma_f32_16x16x32_bf16(am, bm[cp],  cacc, 0, 0, 0);
                acc[rp][cp] = cacc;
            }
        }
    }

    // ---- row-side: per row, top-5 of this wave's 64-col segment ---------
    // C layout: elem (rp,cp,reg) = row wr+rp*16+lg*4+reg, col wc+cp*16+fr.
    {
        int slotR = 2 * tj + (wc >> 6);
        int c0 = Cc + wc + fr;
#pragma unroll
        for (int rp = 0; rp < 4; ++rp) {
#pragma unroll
            for (int reg = 0; reg < 4; ++reg) {
                int grow = R + wr + rp * 16 + lg * 4 + reg;
                float v0 = acc[rp][0][reg], v1 = acc[rp][1][reg];
                float v2 = acc[rp][2][reg], v3 = acc[rp][3][reg];
                if (ti == tj) {     // mask diagonal
                    v0 = (c0      == grow) ? -FLT_MAX : v0;
                    v1 = (c0 + 16 == grow) ? -FLT_MAX : v1;
                    v2 = (c0 + 32 == grow) ? -FLT_MAX : v2;
                    v3 = (c0 + 48 == grow) ? -FLT_MAX : v3;
                }
                ull w[5];
#pragma unroll
                for (int t = 0; t < 5; ++t) {
                    float bv = v0; int bc = c0;     // ascending-col scan, strict >
                    if (v1 > bv) { bv = v1; bc = c0 + 16; }
                    if (v2 > bv) { bv = v2; bc = c0 + 32; }
                    if (v3 > bv) { bv = v3; bc = c0 + 48; }
#pragma unroll
                    for (int o = 1; o < 16; o <<= 1) {
                        float ov = __shfl_xor(bv, o);
                        int   oc = __shfl_xor(bc, o);
                        if (ov > bv || (ov == bv && oc < bc)) { bv = ov; bc = oc; }
                    }
                    w[t] = mkkey(bv, bc);
                    v0 = (bc == c0)      ? -FLT_MAX : v0;
                    v1 = (bc == c0 + 16) ? -FLT_MAX : v1;
                    v2 = (bc == c0 + 32) ? -FLT_MAX : v2;
                    v3 = (bc == c0 + 48) ? -FLT_MAX : v3;
                }
                if (fr == 0) {
                    ull* o = cand + ((base + grow) * 16 + slotR) * 5;
                    o[0] = w[0]; o[1] = w[1]; o[2] = w[2]; o[3] = w[3]; o[4] = w[4];
                }
            }
        }
    }

    // ---- mirror-side: per col (node), top-5 over the 64 tile rows -------
    if (ti != tj) {
        int slotM = 2 * ti + (wr >> 6);
        int nbase = R + wr + lg * 4;    // this lane's neighbor-idx base
#pragma unroll
        for (int cp = 0; cp < 4; ++cp) {
            float mv[16];
#pragma unroll
            for (int rp = 0; rp < 4; ++rp)
#pragma unroll
                for (int reg = 0; reg < 4; ++reg)
                    mv[rp * 4 + reg] = acc[rp][cp][reg];
            ull w[5];
#pragma unroll
            for (int t = 0; t < 5; ++t) {
                float bv = mv[0]; int bn = nbase;   // ascending-idx scan
#pragma unroll
                for (int e = 1; e < 16; ++e) {
                    int n = nbase + (e >> 2) * 16 + (e & 3);
                    if (mv[e] > bv) { bv = mv[e]; bn = n; }
                }
                {   float ov = __shfl_xor(bv, 16); int on = __shfl_xor(bn, 16);
                    if (ov > bv || (ov == bv && on < bn)) { bv = ov; bn = on; } }
                {   float ov = __shfl_xor(bv, 32); int on = __shfl_xor(bn, 32);
                    if (ov > bv || (ov == bv && on < bn)) { bv = ov; bn = on; } }
                w[t] = mkkey(bv, bn);
#pragma unroll
                for (int e = 0; e < 16; ++e) {
                    int n = nbase + (e >> 2) * 16 + (e & 3);
                    mv[e] = (n == bn) ? -FLT_MAX : mv[e];
                }
            }
            if (lg == 0) {
                int node = Cc + wc + cp * 16 + fr;
                ull* o = cand + ((base + node) * 16 + slotM) * 5;
                o[0] = w[0]; o[1] = w[1]; o[2] = w[2]; o[3] = w[3]; o[4] = w[4];
            }
        }
    }
}

// ---- 3. merge: global top-5 of 16 slots x 5 sorted keys per row ---------
__global__ __launch_bounds__(256) void k_merge(const ull* __restrict__ cand,
                                               int* __restrict__ idx) {
    int row = blockIdx.x * 16 + (threadIdx.x >> 4);
    int g   = threadIdx.x & 15;
    const ull* cp = cand + ((size_t)row * 16 + g) * 5;
    ull k0 = cp[0], k1 = cp[1], k2 = cp[2], k3 = cp[3], k4 = cp[4];
    int* op = idx + (size_t)row * KK;
#pragma unroll
    for (int t = 0; t < 5; ++t) {
        ull w = k0;
#pragma unroll
        for (int o = 1; o < 16; o <<= 1) {
            ull x = __shfl_xor(w, o); if (x > w) w = x;
        }
        if (g == t) op[t] = 1023 - (int)(w & 0xFFFFFFFFu);
        bool adv = (k0 == w);
        k0 = adv ? k1 : k0; k1 = adv ? k2 : k1;
        k2 = adv ? k3 : k2; k3 = adv ? k4 : k3; k4 = adv ? 0ULL : k4;
    }
}

// ---- 4. fused gcn: out = res + relu( agg(h,idx) @ W^T + bias ) ----------
#define SW(c) ((c) + 4 * ((c) >> 5))

__global__ __launch_bounds__(256, 3) void k_gcn(const float* __restrict__ h,
                                                const int* __restrict__ idx,
                                                const float* __restrict__ W,
                                                const float* __restrict__ bias,
                                                const float* __restrict__ res,
                                                float* __restrict__ out) {
    int rt = blockIdx.x << 6;
    __shared__ float As[64][132];
    __shared__ float Bs[32][140];
    int tid = threadIdx.x;

    {   // gather + aggregate full rows
        int row = tid >> 2, fq = tid & 3;
        int grow = rt + row;
        const int* ip = idx + (size_t)grow * KK;
        const float* hb = h + (((size_t)grow >> 10) << 10) * DD;
        const float* hs = h + (size_t)grow * DD;
        int n0 = ip[0], n1 = ip[1], n2 = ip[2], n3 = ip[3], n4 = ip[4];
        const float* p0 = hb + (size_t)n0 * DD;
        const float* p1 = hb + (size_t)n1 * DD;
        const float* p2 = hb + (size_t)n2 * DD;
        const float* p3 = hb + (size_t)n3 * DD;
        const float* p4 = hb + (size_t)n4 * DD;
        const float cc = 1.0f / 6.0f;
#pragma unroll
        for (int rep = 0; rep < 8; ++rep) {
            int c = rep * 16 + fq * 4;
            float4 v  = *reinterpret_cast<const float4*>(hs + c);
            float4 u0 = *reinterpret_cast<const float4*>(p0 + c);
            float4 u1 = *reinterpret_cast<const float4*>(p1 + c);
            float4 u2 = *reinterpret_cast<const float4*>(p2 + c);
            float4 u3 = *reinterpret_cast<const float4*>(p3 + c);
            float4 u4 = *reinterpret_cast<const float4*>(p4 + c);
            v.x = (v.x + u0.x + u1.x + u2.x + u3.x + u4.x) * cc;
            v.y = (v.y + u0.y + u1.y + u2.y + u3.y + u4.y) * cc;
            v.z = (v.z + u0.z + u1.z + u2.z + u3.z + u4.z) * cc;
            v.w = (v.w + u0.w + u1.w + u2.w + u3.w + u4.w) * cc;
            *reinterpret_cast<float4*>(&As[row][c]) = v;
        }
    }

    int tr  = (tid >> 4) << 2;
    int tc  = (tid & 15) << 3;
    int stc = SW(tc);

    float acc[4][8];
#pragma unroll
    for (int i = 0; i < 4; ++i)
#pragma unroll
        for (int j = 0; j < 8; ++j) acc[i][j] = 0.f;

    for (int kc = 0; kc < 4; ++kc) {
        __syncthreads();
        {   // stage W chunk k-major into Bs[k][SW(hcol)]
            int hcol = tid >> 1, kq = tid & 1;
            int swc = SW(hcol);
#pragma unroll
            for (int rep = 0; rep < 4; ++rep) {
                int f4i = rep * 2 + kq;
                const float4 v = *reinterpret_cast<const float4*>(
                    W + (size_t)hcol * DD + kc * 32 + f4i * 4);
                int k = f4i * 4;
                Bs[k + 0][swc] = v.x; Bs[k + 1][swc] = v.y;
                Bs[k + 2][swc] = v.z; Bs[k + 3][swc] = v.w;
            }
        }
        __syncthreads();
#pragma unroll 4
        for (int k = 0; k < 32; ++k) {
            int ck = kc * 32 + k;
            const float av[4] = {As[tr + 0][ck], As[tr + 1][ck],
                                 As[tr + 2][ck], As[tr + 3][ck]};
            const float4 b0 = *reinterpret_cast<const float4*>(&Bs[k][stc]);
            const float4 b1 = *reinterpret_cast<const float4*>(&Bs[k][stc + 4]);
            const float bw[8] = {b0.x, b0.y, b0.z, b0.w, b1.x, b1.y, b1.z, b1.w};
#pragma unroll
            for (int ii = 0; ii < 4; ++ii)
#pragma unroll
                for (int jj = 0; jj < 8; ++jj)
                    acc[ii][jj] = fmaf(av[ii], bw[jj], acc[ii][jj]);
        }
    }
    const float4 bz0 = *reinterpret_cast<const float4*>(bias + tc);
    const float4 bz1 = *reinterpret_cast<const float4*>(bias + tc + 4);
    const float bb[8] = {bz0.x, bz0.y, bz0.z, bz0.w, bz1.x, bz1.y, bz1.z, bz1.w};
#pragma unroll
    for (int i = 0; i < 4; ++i) {
        size_t ro = (size_t)(rt + tr + i) * DD + tc;
        const float4 r0 = *reinterpret_cast<const float4*>(res + ro);
        const float4 r1 = *reinterpret_cast<const float4*>(res + ro + 4);
        float4 o0, o1;
        o0.x = r0.x + fmaxf(acc[i][0] + bb[0], 0.f);
        o0.y = r0.y + fmaxf(acc[i][1] + bb[1], 0.f);
        o0.z = r0.z + fmaxf(acc[i][2] + bb[2], 0.f);
        o0.w = r0.w + fmaxf(acc[i][3] + bb[3], 0.f);
        o1.x = r1.x + fmaxf(acc[i][4] + bb[4], 0.f);
        o1.y = r1.y + fmaxf(acc[i][5] + bb[5], 0.f);
        o1.z = r1.z + fmaxf(acc[i][6] + bb[6], 0.f);
        o1.w = r1.w + fmaxf(acc[i][7] + bb[7], 0.f);
        *reinterpret_cast<float4*>(out + ro)     = o0;
        *reinterpret_cast<float4*>(out + ro + 4) = o1;
    }
}

extern "C" void kernel_launch(void* const* d_in, const int* in_sizes, int n_in,
                              void* d_out, int out_size, void* d_ws, size_t ws_size,
                              hipStream_t stream) {
    const float* x  = (const float*)d_in[0];
    const float* W1 = (const float*)d_in[1];
    const float* b1 = (const float*)d_in[2];
    const float* W2 = (const float*)d_in[3];
    const float* b2 = (const float*)d_in[4];
    float* out = (float*)d_out;

    char* ws = (char*)d_ws;
    size_t pl_b   = (size_t)BB * NN * DD * 2;
    size_t h1_b   = (size_t)BB * NN * DD * 4;
    size_t idx_b  = (size_t)BB * NN * KK * 4;
    unsigned short* ph = (unsigned short*)ws;  ws += pl_b;
    unsigned short* pm = (unsigned short*)ws;  ws += pl_b;
    unsigned short* pl = (unsigned short*)ws;  ws += pl_b;
    float* h1  = (float*)ws;                   ws += h1_b;
    int*   idx = (int*)ws;                     ws += idx_b;
    ull*  cand = (ull*)ws;                     // 21 MB

    k_norm<<<BB * NN / 4, 256, 0, stream>>>(x, ph, pm, pl);
    k_sim<<<BB * 36, 256, 0, stream>>>(ph, pm, pl, cand);
    k_merge<<<BB * NN / 16, 256, 0, stream>>>(cand, idx);
    k_gcn<<<BB * NN / 64, 256, 0, stream>>>(x,  idx, W1, b1, x,  h1);
    k_gcn<<<BB * NN / 64, 256, 0, stream>>>(h1, idx, W2, b2, h1, out);
}

// Round 9
// 142.300 us; speedup vs baseline: 1.5532x; 1.5532x over previous
//
#include <hip/hip_runtime.h>
#include <float.h>
#include <math.h>

#define BB 32
#define NN 1024
#define DD 128
#define KK 5

typedef __attribute__((ext_vector_type(8))) short bf16x8;
typedef __attribute__((ext_vector_type(4))) float f32x4;

// rtne f32->bf16 bit trick (no NaN/inf in this problem)
__device__ __forceinline__ unsigned short f2bf(float f) {
    unsigned int u = __float_as_uint(f);
    return (unsigned short)((u + 0x7FFFu + ((u >> 16) & 1u)) >> 16);
}
__device__ __forceinline__ float bf2f(unsigned short h) {
    return __uint_as_float(((unsigned int)h) << 16);
}

// split 8 contiguous f32 into 2 bf16 limbs (hi + mid), rtne
__device__ __forceinline__ void split2(const float4& a0, const float4& a1,
                                       bf16x8& hi, bf16x8& lo) {
    float v[8] = {a0.x, a0.y, a0.z, a0.w, a1.x, a1.y, a1.z, a1.w};
#pragma unroll
    for (int j = 0; j < 8; ++j) {
        unsigned short hb = f2bf(v[j]);
        float r = v[j] - bf2f(hb);
        unsigned short mb = f2bf(r);
        hi[j] = (short)hb;
        lo[j] = (short)mb;
    }
}

// ---- 1. fused: row L2-normalize + 3-limb bf16 split (h,m,l planes) ------
__global__ __launch_bounds__(256) void k_norm(const float* __restrict__ x,
                                              unsigned short* __restrict__ ph,
                                              unsigned short* __restrict__ pm,
                                              unsigned short* __restrict__ pl) {
    int row  = blockIdx.x * 4 + (threadIdx.x >> 6);
    int lane = threadIdx.x & 63;
    float2 v = *reinterpret_cast<const float2*>(x + (size_t)row * DD + lane * 2);
    float ss = v.x * v.x + v.y * v.y;
#pragma unroll
    for (int o = 32; o >= 1; o >>= 1) ss += __shfl_xor(ss, o);
    float inv = 1.0f / fmaxf(sqrtf(ss), 1e-12f);
    float y0 = v.x * inv, y1 = v.y * inv;

    unsigned short h0 = f2bf(y0);             float r0 = y0 - bf2f(h0);
    unsigned short m0 = f2bf(r0);             float s0 = r0 - bf2f(m0);
    unsigned short l0 = f2bf(s0);
    unsigned short h1 = f2bf(y1);             float r1 = y1 - bf2f(h1);
    unsigned short m1 = f2bf(r1);             float s1 = r1 - bf2f(m1);
    unsigned short l1 = f2bf(s1);

    size_t o = (size_t)row * DD + lane * 2;
    *reinterpret_cast<unsigned int*>(ph + o) = (unsigned int)h0 | ((unsigned int)h1 << 16);
    *reinterpret_cast<unsigned int*>(pm + o) = (unsigned int)m0 | ((unsigned int)m1 << 16);
    *reinterpret_cast<unsigned int*>(pl + o) = (unsigned int)l0 | ((unsigned int)l1 << 16);
}

union SMem {
    struct {
        unsigned short Ah[128][40], Am[128][40], Al[128][40];
        unsigned short Bh[128][40], Bm[128][40], Bl[128][40];
    } s;                      // 61440 B (MFMA staging)
    float q[4][32][68];       // 34816 B (per-wave transpose scratch)
};

__device__ __forceinline__ void stage_plane(const unsigned short* __restrict__ g,
                                            unsigned short (*s)[40], int tid,
                                            size_t rowbase, int c) {
#pragma unroll
    for (int hh = 0; hh < 2; ++hh) {
        int u = tid + (hh << 8);
        int row = u >> 2, qq = u & 3;
        const float4 v = *reinterpret_cast<const float4*>(
            g + (rowbase + row) * DD + (c << 5) + (qq << 3));
        *reinterpret_cast<float4*>(&s[row][qq << 3]) = v;
    }
}

// ---- 2. sim = xn.xn^T via 6-limb MFMA, upper-tri tiles, full-sector stores
__global__ __launch_bounds__(256, 2) void k_sim(const unsigned short* __restrict__ ph,
                                                const unsigned short* __restrict__ pm,
                                                const unsigned short* __restrict__ pl,
                                                float* __restrict__ sim) {
    // XCD-chunked bijective swizzle: 1152 = 8 * 144
    int bid = blockIdx.x;
    int lb  = (bid & 7) * 144 + (bid >> 3);
    int bl  = lb / 36;
    int p   = lb - bl * 36;
    int ti = 0;
    while (p >= 8 - ti) { p -= 8 - ti; ++ti; }
    int tj = ti + p;
    int R  = ti << 7, Cc = tj << 7;

    __shared__ SMem sm;

    int tid  = threadIdx.x;
    int wv   = tid >> 6;
    int lane = tid & 63;
    int wr = (wv >> 1) << 6;
    int wc = (wv & 1) << 6;
    int lg = lane >> 4, fr = lane & 15;

    size_t base = (size_t)bl * NN;
    size_t rbA = base + R, rbB = base + Cc;

    f32x4 acc[4][4];
#pragma unroll
    for (int i = 0; i < 4; ++i)
#pragma unroll
        for (int j = 0; j < 4; ++j) acc[i][j] = (f32x4){0.f, 0.f, 0.f, 0.f};

    int kk = lg << 3;

    for (int c = 0; c < 4; ++c) {
        if (c) __syncthreads();
        stage_plane(ph, sm.s.Ah, tid, rbA, c);
        stage_plane(pm, sm.s.Am, tid, rbA, c);
        stage_plane(pl, sm.s.Al, tid, rbA, c);
        stage_plane(ph, sm.s.Bh, tid, rbB, c);
        stage_plane(pm, sm.s.Bm, tid, rbB, c);
        stage_plane(pl, sm.s.Bl, tid, rbB, c);
        __syncthreads();

        bf16x8 bh[4], bm[4], blo[4];
#pragma unroll
        for (int cp = 0; cp < 4; ++cp) {
            int rb = wc + cp * 16 + fr;
            bh[cp]  = *reinterpret_cast<const bf16x8*>(&sm.s.Bh[rb][kk]);
            bm[cp]  = *reinterpret_cast<const bf16x8*>(&sm.s.Bm[rb][kk]);
            blo[cp] = *reinterpret_cast<const bf16x8*>(&sm.s.Bl[rb][kk]);
        }
#pragma unroll
        for (int rp = 0; rp < 4; ++rp) {
            int ra = wr + rp * 16 + fr;
            bf16x8 ah = *reinterpret_cast<const bf16x8*>(&sm.s.Ah[ra][kk]);
            bf16x8 am = *reinterpret_cast<const bf16x8*>(&sm.s.Am[ra][kk]);
            bf16x8 al = *reinterpret_cast<const bf16x8*>(&sm.s.Al[ra][kk]);
#pragma unroll
            for (int cp = 0; cp < 4; ++cp) {
                f32x4 cacc = acc[rp][cp];
                cacc = __builtin_amdgcn_mfma_f32_16x16x32_bf16(ah, bh[cp],  cacc, 0, 0, 0);
                cacc = __builtin_amdgcn_mfma_f32_16x16x32_bf16(ah, bm[cp],  cacc, 0, 0, 0);
                cacc = __builtin_amdgcn_mfma_f32_16x16x32_bf16(am, bh[cp],  cacc, 0, 0, 0);
                cacc = __builtin_amdgcn_mfma_f32_16x16x32_bf16(ah, blo[cp], cacc, 0, 0, 0);
                cacc = __builtin_amdgcn_mfma_f32_16x16x32_bf16(al, bh[cp],  cacc, 0, 0, 0);
                cacc = __builtin_amdgcn_mfma_f32_16x16x32_bf16(am, bm[cp],  cacc, 0, 0, 0);
                acc[rp][cp] = cacc;
            }
        }
    }

    __syncthreads();   // staging LDS dead -> reuse union as per-wave q[]
    float (*q)[68] = sm.q[wv];
    float* Cb = sim + base * NN;

    // ---- mirror block (tj,ti): transpose to q[col][row], 1KB stores ------
    if (ti != tj) {
#pragma unroll
        for (int hp = 0; hp < 2; ++hp) {
#pragma unroll
            for (int rp = 0; rp < 4; ++rp)
#pragma unroll
                for (int cpl = 0; cpl < 2; ++cpl) {
                    const f32x4 a = acc[rp][2 * hp + cpl];
                    *reinterpret_cast<float4*>(&q[cpl * 16 + fr][rp * 16 + lg * 4]) =
                        make_float4(a[0], a[1], a[2], a[3]);
                }
#pragma unroll
            for (int it = 0; it < 8; ++it) {
                int lcol = lg + 4 * it;
                const float4 v = *reinterpret_cast<const float4*>(&q[lcol][fr * 4]);
                *reinterpret_cast<float4*>(
                    &Cb[(size_t)(Cc + wc + 32 * hp + lcol) * NN + R + wr + fr * 4]) = v;
            }
        }
    }
    // ---- row block (ti,tj): transpose to q[row][col], 1KB stores ---------
#pragma unroll
    for (int hr = 0; hr < 2; ++hr) {
#pragma unroll
        for (int rpl = 0; rpl < 2; ++rpl)
#pragma unroll
            for (int cp = 0; cp < 4; ++cp)
#pragma unroll
                for (int reg = 0; reg < 4; ++reg)
                    q[rpl * 16 + lg * 4 + reg][cp * 16 + fr] = acc[2 * hr + rpl][cp][reg];
#pragma unroll
        for (int it = 0; it < 8; ++it) {
            int lrow = lg + 4 * it;
            const float4 v = *reinterpret_cast<const float4*>(&q[lrow][fr * 4]);
            *reinterpret_cast<float4*>(
                &Cb[(size_t)(R + wr + 32 * hr + lrow) * NN + Cc + wc + fr * 4]) = v;
        }
    }
}

// ---------------- 3. top-5 per row (wave per row) ------------------------
__global__ __launch_bounds__(256) void k_topk(const float* __restrict__ sim,
                                              int* __restrict__ idx) {
    int lrow = blockIdx.x * 4 + (threadIdx.x >> 6);
    int lane = threadIdx.x & 63;
    const float* sr = sim + (size_t)lrow * NN;
    int i = lrow & (NN - 1);

    float v[16];
#pragma unroll
    for (int q = 0; q < 4; ++q) {
        float4 f = *reinterpret_cast<const float4*>(sr + lane * 16 + q * 4);
        v[q * 4 + 0] = f.x; v[q * 4 + 1] = f.y; v[q * 4 + 2] = f.z; v[q * 4 + 3] = f.w;
    }
    if ((i >> 4) == lane) {
        int s = i & 15;
#pragma unroll
        for (int j = 0; j < 16; ++j) if (j == s) v[j] = -FLT_MAX;
    }
    int* op = idx + (size_t)lrow * KK;
#pragma unroll
    for (int t = 0; t < KK; ++t) {
        float bv = v[0]; int bj = 0;
#pragma unroll
        for (int j = 1; j < 16; ++j) if (v[j] > bv) { bv = v[j]; bj = j; }
        int bm = (lane << 4) + bj;
#pragma unroll
        for (int o = 1; o < 64; o <<= 1) {
            float ov = __shfl_xor(bv, o);
            int   om = __shfl_xor(bm, o);
            if (ov > bv || (ov == bv && om < bm)) { bv = ov; bm = om; }
        }
        if ((bm >> 4) == lane) {
            int s = bm & 15;
#pragma unroll
            for (int j = 0; j < 16; ++j) if (j == s) v[j] = -FLT_MAX;
        }
        if (lane == 0) op[t] = bm;
    }
}

// ---- 4. fused gcn via 2-limb bf16 MFMA --------------------------------
// out = res + relu( agg(h,idx) @ W^T + bias ), 64-row tiles, 4 blocks/CU.
// A: fp32 LDS + in-reg split; W: fragments straight from global + split.
__global__ __launch_bounds__(256, 3) void k_gcn(const float* __restrict__ h,
                                                const int* __restrict__ idx,
                                                const float* __restrict__ W,
                                                const float* __restrict__ bias,
                                                const float* __restrict__ res,
                                                float* __restrict__ out) {
    int rt = blockIdx.x << 6;
    __shared__ float As[64][132];      // 33792 B
    int tid = threadIdx.x;

    {   // gather + aggregate full rows (fp32)
        int row = tid >> 2, fq = tid & 3;
        int grow = rt + row;
        const int* ip = idx + (size_t)grow * KK;
        const float* hb = h + (((size_t)grow >> 10) << 10) * DD;
        const float* hs = h + (size_t)grow * DD;
        int n0 = ip[0], n1 = ip[1], n2 = ip[2], n3 = ip[3], n4 = ip[4];
        const float* p0 = hb + (size_t)n0 * DD;
        const float* p1 = hb + (size_t)n1 * DD;
        const float* p2 = hb + (size_t)n2 * DD;
        const float* p3 = hb + (size_t)n3 * DD;
        const float* p4 = hb + (size_t)n4 * DD;
        const float cc = 1.0f / 6.0f;
#pragma unroll
        for (int rep = 0; rep < 8; ++rep) {
            int c = rep * 16 + fq * 4;
            float4 v  = *reinterpret_cast<const float4*>(hs + c);
            float4 u0 = *reinterpret_cast<const float4*>(p0 + c);
            float4 u1 = *reinterpret_cast<const float4*>(p1 + c);
            float4 u2 = *reinterpret_cast<const float4*>(p2 + c);
            float4 u3 = *reinterpret_cast<const float4*>(p3 + c);
            float4 u4 = *reinterpret_cast<const float4*>(p4 + c);
            v.x = (v.x + u0.x + u1.x + u2.x + u3.x + u4.x) * cc;
            v.y = (v.y + u0.y + u1.y + u2.y + u3.y + u4.y) * cc;
            v.z = (v.z + u0.z + u1.z + u2.z + u3.z + u4.z) * cc;
            v.w = (v.w + u0.w + u1.w + u2.w + u3.w + u4.w) * cc;
            *reinterpret_cast<float4*>(&As[row][c]) = v;
        }
    }
    __syncthreads();

    int wv   = tid >> 6;
    int lane = tid & 63;
    int wr = (wv >> 1) << 5;     // wave row-tile: 0 / 32
    int wc = (wv & 1) << 6;      // wave col-tile: 0 / 64
    int lg = lane >> 4, fr = lane & 15;

    f32x4 acc[2][4];
#pragma unroll
    for (int i = 0; i < 2; ++i)
#pragma unroll
        for (int j = 0; j < 4; ++j) acc[i][j] = (f32x4){0.f, 0.f, 0.f, 0.f};

#pragma unroll
    for (int kc = 0; kc < 4; ++kc) {
        int k0 = kc * 32 + lg * 8;
        bf16x8 ahh[2], ahm[2];
#pragma unroll
        for (int rp = 0; rp < 2; ++rp) {
            const float* ap = &As[wr + rp * 16 + fr][k0];
            split2(*reinterpret_cast<const float4*>(ap),
                   *reinterpret_cast<const float4*>(ap + 4), ahh[rp], ahm[rp]);
        }
        bf16x8 bhh[4], bhm[4];
#pragma unroll
        for (int cp = 0; cp < 4; ++cp) {
            const float* wp = W + (size_t)(wc + cp * 16 + fr) * DD + k0;
            split2(*reinterpret_cast<const float4*>(wp),
                   *reinterpret_cast<const float4*>(wp + 4), bhh[cp], bhm[cp]);
        }
#pragma unroll
        for (int rp = 0; rp < 2; ++rp)
#pragma unroll
            for (int cp = 0; cp < 4; ++cp) {
                f32x4 c = acc[rp][cp];
                c = __builtin_amdgcn_mfma_f32_16x16x32_bf16(ahh[rp], bhh[cp], c, 0, 0, 0);
                c = __builtin_amdgcn_mfma_f32_16x16x32_bf16(ahh[rp], bhm[cp], c, 0, 0, 0);
                c = __builtin_amdgcn_mfma_f32_16x16x32_bf16(ahm[rp], bhh[cp], c, 0, 0, 0);
                acc[rp][cp] = c;
            }
    }

    __syncthreads();
    // stage output back through As (full-sector stores)
#pragma unroll
    for (int rp = 0; rp < 2; ++rp)
#pragma unroll
        for (int cp = 0; cp < 4; ++cp)
#pragma unroll
            for (int reg = 0; reg < 4; ++reg)
                As[wr + rp * 16 + lg * 4 + reg][wc + cp * 16 + fr] = acc[rp][cp][reg];
    __syncthreads();

#pragma unroll
    for (int rep = 0; rep < 8; ++rep) {
        int slot = tid + rep * 256;
        int row  = slot >> 5;
        int c4   = (slot & 31) << 2;
        float4 v  = *reinterpret_cast<const float4*>(&As[row][c4]);
        size_t go = (size_t)(rt + row) * DD + c4;
        const float4 r  = *reinterpret_cast<const float4*>(res + go);
        const float4 bz = *reinterpret_cast<const float4*>(bias + c4);
        float4 o;
        o.x = r.x + fmaxf(v.x + bz.x, 0.f);
        o.y = r.y + fmaxf(v.y + bz.y, 0.f);
        o.z = r.z + fmaxf(v.z + bz.z, 0.f);
        o.w = r.w + fmaxf(v.w + bz.w, 0.f);
        *reinterpret_cast<float4*>(out + go) = o;
    }
}

extern "C" void kernel_launch(void* const* d_in, const int* in_sizes, int n_in,
                              void* d_out, int out_size, void* d_ws, size_t ws_size,
                              hipStream_t stream) {
    const float* x  = (const float*)d_in[0];
    const float* W1 = (const float*)d_in[1];
    const float* b1 = (const float*)d_in[2];
    const float* W2 = (const float*)d_in[3];
    const float* b2 = (const float*)d_in[4];
    float* out = (float*)d_out;

    char* ws = (char*)d_ws;
    size_t pl_b  = (size_t)BB * NN * DD * 2;
    size_t h1_b  = (size_t)BB * NN * DD * 4;
    size_t idx_b = (size_t)BB * NN * KK * 4;
    unsigned short* ph = (unsigned short*)ws;  ws += pl_b;
    unsigned short* pm = (unsigned short*)ws;  ws += pl_b;
    unsigned short* pl = (unsigned short*)ws;  ws += pl_b;
    float* h1  = (float*)ws;                   ws += h1_b;
    int*   idx = (int*)ws;                     ws += idx_b;
    float* sim = (float*)ws;   // 134 MB

    k_norm<<<BB * NN / 4, 256, 0, stream>>>(x, ph, pm, pl);
    k_sim<<<BB * 36, 256, 0, stream>>>(ph, pm, pl, sim);
    k_topk<<<BB * NN / 4, 256, 0, stream>>>(sim, idx);
    k_gcn<<<BB * NN / 64, 256, 0, stream>>>(x,  idx, W1, b1, x,  h1);
    k_gcn<<<BB * NN / 64, 256, 0, stream>>>(h1, idx, W2, b2, h1, out);
}